// Round 11
// baseline (34.607 us; speedup 1.0000x reference)
//
#include <hip/hip_runtime.h>
#include <hip/hip_bf16.h>
#include <math.h>

// Problem constants (fixed by setup_inputs)
#define NB 8
#define NC 256
#define HW 16384          // 128*128
#define NP 64
#define PXW 32            // pixels per wave (2 n-tiles)
#define PXB 128           // pixels per block (4 waves)

typedef __attribute__((ext_vector_type(8))) short bf16x8;
typedef __attribute__((ext_vector_type(4))) int   i32x4;
typedef __attribute__((ext_vector_type(4))) float f32x4;

__device__ __forceinline__ ushort f2bf_rtne(float v) {
    unsigned u = __builtin_bit_cast(unsigned, v);
    u += 0x7fffu + ((u >> 16) & 1u);
    return (ushort)(u >> 16);
}

__device__ __forceinline__ bf16x8 pack_bf8(const float* f) {
    i32x4 bi;
    #pragma unroll
    for (int j = 0; j < 4; ++j) {
        __hip_bfloat162 h = __float22bfloat162_rn(make_float2(f[2*j], f[2*j+1]));
        int r;
        __builtin_memcpy(&r, &h, 4);            // bit-move; cvt_pk fusion intact
        bi[j] = r;
    }
    return __builtin_bit_cast(bf16x8, bi);
}

// Single fused kernel. Block = 256 threads (4 waves), 128 pixels.
// B (feats) loaded as float2 (2 px / lane) -> half the VMEM instructions;
// a 1-inst __shfl_xor pair-exchange restores the per-lane fragment layout.
// A (centers) rebuilt per block into XOR-swizzled LDS (round-9 design).
__global__ __launch_bounds__(256) void geo_fused(
    const float* __restrict__ feats,     // (B,C,H,W) fp32
    const float* __restrict__ cm,        // (P,K)
    const float* __restrict__ alpha,     // (P,1)
    const float* __restrict__ gamma_,    // (P,1)
    const float* __restrict__ centers,   // (P,C)
    const float* __restrict__ geo,       // (P,1)
    float* __restrict__ out)             // (B,3,H,W)
{
    __shared__ __align__(16) char sAbuf[NP*512];   // 32 KB swizzled A image
    __shared__ float sG2[NP], sE2[NP], sU0[NP], sU1[NP];
    _Float16 (*sSh)[PXB + 4] = (_Float16 (*)[PXB + 4])sAbuf;  // overlay

    const int tid  = threadIdx.x;
    const int lane = tid & 63;
    const int wu   = tid >> 6;           // wave id 0..3
    const int col  = lane & 15;          // pixel-in-tile / A proto-row
    const int kg   = lane >> 4;          // k-group 0..3 (8 channels each)
    const int swz  = (col & 7) << 4;     // T2 swizzle
    const int cpar = col & 1;            // pixel-pair parity

    const int pix0 = blockIdx.x * PXB;
    const int b    = pix0 >> 14;
    const int hw0  = pix0 & (HW - 1);
    // pair-base pointers: this lane's float2 covers px {col&~1, col|1}
    const float* __restrict__ fpq0 = feats + (size_t)b * NC * HW + hw0 + wu*PXW + (col & ~1);
    const float* __restrict__ fpq1 = fpq0 + 16;

    // B loads: 4 float2 per pixel-group per k-step; channel = kg*8 + 2j + cpar
    #define LOADB(G0, G1, KS)                                                 \
    {                                                                         \
        _Pragma("unroll")                                                     \
        for (int j = 0; j < 4; ++j) {                                         \
            const size_t off = (size_t)((KS)*32 + kg*8 + 2*j + cpar) * HW;    \
            G0[j] = *(const float2*)&fpq0[off];                               \
            G1[j] = *(const float2*)&fpq1[off];                               \
        }                                                                     \
    }

    // pair exchange: even lane keeps .x (own px, even ch), sends .y;
    // odd lane keeps .y (own px, odd ch), sends .x. One shfl per float2.
    #define EXCH(G, F)                                                       \
    {                                                                        \
        _Pragma("unroll")                                                    \
        for (int j = 0; j < 4; ++j) {                                        \
            const float sv = cpar ? G[j].x : G[j].y;                         \
            const float rv = __shfl_xor(sv, 1);                              \
            F[2*j]   = cpar ? rv : G[j].x;                                   \
            F[2*j+1] = cpar ? G[j].y : rv;                                   \
        }                                                                    \
    }

    // ---- Phase 0: B prologue (2 k-steps in flight before A-build) ----
    float2 gA0[4], gA1[4], gB0[4], gB1[4];
    LOADB(gA0, gA1, 0)
    LOADB(gB0, gB1, 1)

    // ---- Phase 1: A-build (covers B latency) ----
    {
        float gs = geo[lane];
        #pragma unroll
        for (int d = 1; d < 64; d <<= 1) gs += __shfl_xor(gs, d);
        const float scale = 1.0f + 0.1f * tanhf(gs * (1.0f / NP));

        const int p  = tid >> 2;
        const int cb = tid & 3;
        float psq = 0.f;
        #pragma unroll 4
        for (int j = 0; j < 16; ++j) {
            const int c = cb*4 + j*16;
            const float4 cv = *(const float4*)&centers[p*NC + c];
            const float c0 = cv.x * scale, c1 = cv.y * scale;
            const float c2 = cv.z * scale, c3 = cv.w * scale;
            psq += c0*c0 + c1*c1 + c2*c2 + c3*c3;
            ushort4 ub;
            ub.x = f2bf_rtne(c0); ub.y = f2bf_rtne(c1);
            ub.z = f2bf_rtne(c2); ub.w = f2bf_rtne(c3);
            *(ushort4*)(sAbuf + ((p*512 + c*2) ^ ((p & 7) << 4))) = ub;
        }
        psq += __shfl_xor(psq, 1);
        psq += __shfl_xor(psq, 2);

        if (cb == 0) {
            float b0 = cm[2*p+0]; b0 *= b0;
            float b1 = cm[2*p+1]; b1 *= b1;
            sU0[p] = b0 / (b0 + b1);
            sU1[p] = b1 / (b0 + b1);
            const float L2E = 1.4426950408889634f;
            const float al  = 0.99f / (1.f + expf(-alpha[p]));
            const float G2  = gamma_[p] * gamma_[p] * L2E;
            sG2[p] = G2;
            sE2[p] = log2f(al) - 0.5f * G2 * psq;
        }
    }
    __syncthreads();

    // ---- Phase 2: MFMA k-loop ----
    f32x4 accA0 = {0,0,0,0}, accA1 = {0,0,0,0}, accA2 = {0,0,0,0}, accA3 = {0,0,0,0};
    f32x4 accB0 = {0,0,0,0}, accB1 = {0,0,0,0}, accB2 = {0,0,0,0}, accB3 = {0,0,0,0};
    float xsq0 = 0.f, xsq1 = 0.f;

    #define KSTEP(G0, G1, KS)                                                 \
    {                                                                         \
        float F0[8], F1[8];                                                   \
        EXCH(G0, F0)                                                          \
        EXCH(G1, F1)                                                          \
        _Pragma("unroll")                                                     \
        for (int j = 0; j < 8; ++j) { xsq0 += F0[j]*F0[j]; xsq1 += F1[j]*F1[j]; } \
        const bf16x8 bf0 = pack_bf8(F0);                                      \
        const bf16x8 bf1 = pack_bf8(F1);                                      \
        const char* abase = sAbuf + ((col*512 + (KS)*64 + kg*16) ^ swz);      \
        const bf16x8 a0 = *(const bf16x8*)(abase + 0*8192);                   \
        const bf16x8 a1 = *(const bf16x8*)(abase + 1*8192);                   \
        const bf16x8 a2 = *(const bf16x8*)(abase + 2*8192);                   \
        const bf16x8 a3 = *(const bf16x8*)(abase + 3*8192);                   \
        accA0 = __builtin_amdgcn_mfma_f32_16x16x32_bf16(a0, bf0, accA0, 0,0,0);\
        accB0 = __builtin_amdgcn_mfma_f32_16x16x32_bf16(a0, bf1, accB0, 0,0,0);\
        accA1 = __builtin_amdgcn_mfma_f32_16x16x32_bf16(a1, bf0, accA1, 0,0,0);\
        accB1 = __builtin_amdgcn_mfma_f32_16x16x32_bf16(a1, bf1, accB1, 0,0,0);\
        accA2 = __builtin_amdgcn_mfma_f32_16x16x32_bf16(a2, bf0, accA2, 0,0,0);\
        accB2 = __builtin_amdgcn_mfma_f32_16x16x32_bf16(a2, bf1, accB2, 0,0,0);\
        accA3 = __builtin_amdgcn_mfma_f32_16x16x32_bf16(a3, bf0, accA3, 0,0,0);\
        accB3 = __builtin_amdgcn_mfma_f32_16x16x32_bf16(a3, bf1, accB3, 0,0,0);\
    }

    #pragma unroll 1
    for (int ks2 = 0; ks2 < 4; ++ks2) {       // 2 k-steps per iteration
        KSTEP(gA0, gA1, 2*ks2)
        if (ks2 < 3) LOADB(gA0, gA1, 2*ks2 + 2)
        KSTEP(gB0, gB1, 2*ks2 + 1)
        if (ks2 < 3) LOADB(gB0, gB1, 2*ks2 + 3)
    }
    #undef KSTEP
    #undef LOADB
    #undef EXCH

    // full x_sq per pixel: reduce over the 4 k-groups
    xsq0 += __shfl_xor(xsq0, 16); xsq0 += __shfl_xor(xsq0, 32);
    xsq1 += __shfl_xor(xsq1, 16); xsq1 += __shfl_xor(xsq1, 32);
    const float xh0 = 0.5f * xsq0;
    const float xh1 = 0.5f * xsq1;

    __syncthreads();   // all waves done reading A -> safe to overlay sSh

    // ---- Phase 3: s_act exchange + evidential scan ----
    const int wpx0 = wu*PXW + col;
    const int wpx1 = wpx0 + 16;
    #define EPI(M, ACC, ACCB)                                                 \
    {                                                                         \
        _Pragma("unroll")                                                     \
        for (int r = 0; r < 4; ++r) {                                         \
            const int p = (M)*16 + kg*4 + r;                                  \
            sSh[p][wpx0] = (_Float16)exp2f(sE2[p] + sG2[p] * (ACC[r]  - xh0));\
            sSh[p][wpx1] = (_Float16)exp2f(sE2[p] + sG2[p] * (ACCB[r] - xh1));\
        }                                                                     \
    }
    EPI(0, accA0, accB0) EPI(1, accA1, accB1)
    EPI(2, accA2, accB2) EPI(3, accA3, accB3)
    #undef EPI
    __syncthreads();

    // sequential evidential scan per pixel (64 steps, registers only)
    if (tid < PXB) {
        float ms0 = 0.f, ms1 = 0.f, mt = 1.f;
        #pragma unroll
        for (int p = 0; p < NP; ++p) {
            const float s   = (float)sSh[p][tid];
            const float mth = 1.f - s;
            const float m0  = s * sU0[p];
            const float m1  = s * sU1[p];
            ms0 = ms0 * (m0 + mth) + m0 * mt;
            ms1 = ms1 * (m1 + mth) + m1 * mt;
            mt *= mth;
        }
        const float inv = 1.f / (ms0 + ms1 + mt + 1e-12f);
        float* __restrict__ op = out + (size_t)b * 3 * HW + hw0 + tid;
        op[0*HW] = ms0 * inv;
        op[1*HW] = ms1 * inv;
        op[2*HW] = mt  * inv;
    }
}

extern "C" void kernel_launch(void* const* d_in, const int* in_sizes, int n_in,
                              void* d_out, int out_size, void* d_ws, size_t ws_size,
                              hipStream_t stream) {
    const float* feats   = (const float*)d_in[0];
    // d_in[1] = geo_context (unused by reference)
    const float* cm      = (const float*)d_in[2];
    const float* alpha   = (const float*)d_in[3];
    const float* gamma_  = (const float*)d_in[4];
    const float* centers = (const float*)d_in[5];
    const float* geo     = (const float*)d_in[6];
    float* out = (float*)d_out;

    const int total = NB * HW;                 // 131072 pixels
    geo_fused<<<total / PXB, 256, 0, stream>>>(feats, cm, alpha, gamma_,
                                               centers, geo, out);
}

// Round 12
// 33.754 us; speedup vs baseline: 1.0253x; 1.0253x over previous
//
#include <hip/hip_runtime.h>
#include <hip/hip_bf16.h>
#include <math.h>

// Problem constants (fixed by setup_inputs)
#define NB 8
#define NC 256
#define HW 16384          // 128*128
#define NP 64
#define PXW 32            // pixels per wave (2 n-tiles)
#define PXB 128           // pixels per block (4 waves)

typedef __attribute__((ext_vector_type(8))) short bf16x8;
typedef __attribute__((ext_vector_type(4))) int   i32x4;
typedef __attribute__((ext_vector_type(4))) float f32x4;

__device__ __forceinline__ ushort f2bf_rtne(float v) {
    unsigned u = __builtin_bit_cast(unsigned, v);
    u += 0x7fffu + ((u >> 16) & 1u);
    return (ushort)(u >> 16);
}

__device__ __forceinline__ bf16x8 pack_bf8(const float* f) {
    i32x4 bi;
    #pragma unroll
    for (int j = 0; j < 4; ++j) {
        __hip_bfloat162 h = __float22bfloat162_rn(make_float2(f[2*j], f[2*j+1]));
        int r;
        __builtin_memcpy(&r, &h, 4);            // bit-move; cvt_pk fusion intact
        bi[j] = r;
    }
    return __builtin_bit_cast(bf16x8, bi);
}

// Single fused kernel (round-10 form — best measured: 33.65 us).
// Block = 256 threads (4 waves), 128 pixels.
// Phase 0: issue first 2 k-steps of B (feats) loads -> in flight.
// Phase 1: A-build — every block scales/converts centers (64 KB, L2-hot)
//          into its own XOR-swizzled LDS image + per-proto constants.
//          This work doubles as latency cover for the B prologue.
// Phase 2: k-loop — 8 MFMA k-steps, A from swizzled LDS (conflict-free
//          ds_read_b128), B via register double-buffer. No barriers.
// Phase 3: epilogue exp2 -> fp16 s_act exchange (overlays A buffer) ->
//          sequential evidential scan (tid<128) -> out.
__global__ __launch_bounds__(256) void geo_fused(
    const float* __restrict__ feats,     // (B,C,H,W) fp32
    const float* __restrict__ cm,        // (P,K)
    const float* __restrict__ alpha,     // (P,1)
    const float* __restrict__ gamma_,    // (P,1)
    const float* __restrict__ centers,   // (P,C)
    const float* __restrict__ geo,       // (P,1)
    float* __restrict__ out)             // (B,3,H,W)
{
    __shared__ __align__(16) char sAbuf[NP*512];   // 32 KB swizzled A image
    __shared__ float sG2[NP], sE2[NP], sU0[NP], sU1[NP];
    _Float16 (*sSh)[PXB + 4] = (_Float16 (*)[PXB + 4])sAbuf;  // overlay

    const int tid  = threadIdx.x;
    const int lane = tid & 63;
    const int wu   = tid >> 6;           // wave id 0..3
    const int col  = lane & 15;          // pixel-in-tile / A proto-row
    const int kg   = lane >> 4;          // k-group 0..3 (8 channels each)
    const int swz  = (col & 7) << 4;     // T2 swizzle

    const int pix0 = blockIdx.x * PXB;
    const int b    = pix0 >> 14;
    const int hw0  = pix0 & (HW - 1);
    const float* __restrict__ fpx0 = feats + (size_t)b * NC * HW + hw0 + wu*PXW + col;
    const float* __restrict__ fpx1 = fpx0 + 16;

    #define LOADB(F0, F1, KS)                                                 \
    {                                                                         \
        _Pragma("unroll")                                                     \
        for (int j = 0; j < 8; ++j) {                                         \
            F0[j] = fpx0[(size_t)((KS)*32 + kg*8 + j) * HW];                  \
            F1[j] = fpx1[(size_t)((KS)*32 + kg*8 + j) * HW];                  \
        }                                                                     \
    }

    // ---- Phase 0: B prologue (32 loads in flight before A-build) ----
    float eA0[8], eA1[8], eB0[8], eB1[8];
    LOADB(eA0, eA1, 0)
    LOADB(eB0, eB1, 1)

    // ---- Phase 1: A-build (covers B latency) ----
    {
        // scale = 1 + 0.1*tanh(mean(geo)); per-wave butterfly (redundant x4)
        float gs = geo[lane];
        #pragma unroll
        for (int d = 1; d < 64; d <<= 1) gs += __shfl_xor(gs, d);
        const float scale = 1.0f + 0.1f * tanhf(gs * (1.0f / NP));

        // thread -> proto p = tid>>2, channel comb cb = tid&3
        const int p  = tid >> 2;
        const int cb = tid & 3;
        float psq = 0.f;
        #pragma unroll 4
        for (int j = 0; j < 16; ++j) {
            const int c = cb*4 + j*16;
            const float4 cv = *(const float4*)&centers[p*NC + c];
            const float c0 = cv.x * scale, c1 = cv.y * scale;
            const float c2 = cv.z * scale, c3 = cv.w * scale;
            psq += c0*c0 + c1*c1 + c2*c2 + c3*c3;
            ushort4 ub;
            ub.x = f2bf_rtne(c0); ub.y = f2bf_rtne(c1);
            ub.z = f2bf_rtne(c2); ub.w = f2bf_rtne(c3);
            // swizzled store: byte = (p*512 + c*2) ^ ((p&7)<<4)
            *(ushort4*)(sAbuf + ((p*512 + c*2) ^ ((p & 7) << 4))) = ub;
        }
        // full psq: reduce over the 4 threads of this proto
        psq += __shfl_xor(psq, 1);
        psq += __shfl_xor(psq, 2);

        if (cb == 0) {
            float b0 = cm[2*p+0]; b0 *= b0;
            float b1 = cm[2*p+1]; b1 *= b1;
            sU0[p] = b0 / (b0 + b1);
            sU1[p] = b1 / (b0 + b1);
            const float L2E = 1.4426950408889634f;
            const float al  = 0.99f / (1.f + expf(-alpha[p]));
            const float G2  = gamma_[p] * gamma_[p] * L2E;
            sG2[p] = G2;
            sE2[p] = log2f(al) - 0.5f * G2 * psq;
            // s_act = exp2(E2 + G2*(x.p - 0.5*x_sq))
        }
    }
    __syncthreads();

    // ---- Phase 2: MFMA k-loop ----
    f32x4 accA0 = {0,0,0,0}, accA1 = {0,0,0,0}, accA2 = {0,0,0,0}, accA3 = {0,0,0,0};
    f32x4 accB0 = {0,0,0,0}, accB1 = {0,0,0,0}, accB2 = {0,0,0,0}, accB3 = {0,0,0,0};
    float xsq0 = 0.f, xsq1 = 0.f;

    #define KSTEP(F0, F1, KS)                                                 \
    {                                                                         \
        _Pragma("unroll")                                                     \
        for (int j = 0; j < 8; ++j) { xsq0 += F0[j]*F0[j]; xsq1 += F1[j]*F1[j]; } \
        const bf16x8 bf0 = pack_bf8(F0);                                      \
        const bf16x8 bf1 = pack_bf8(F1);                                      \
        const char* abase = sAbuf + ((col*512 + (KS)*64 + kg*16) ^ swz);      \
        const bf16x8 a0 = *(const bf16x8*)(abase + 0*8192);                   \
        const bf16x8 a1 = *(const bf16x8*)(abase + 1*8192);                   \
        const bf16x8 a2 = *(const bf16x8*)(abase + 2*8192);                   \
        const bf16x8 a3 = *(const bf16x8*)(abase + 3*8192);                   \
        accA0 = __builtin_amdgcn_mfma_f32_16x16x32_bf16(a0, bf0, accA0, 0,0,0);\
        accB0 = __builtin_amdgcn_mfma_f32_16x16x32_bf16(a0, bf1, accB0, 0,0,0);\
        accA1 = __builtin_amdgcn_mfma_f32_16x16x32_bf16(a1, bf0, accA1, 0,0,0);\
        accB1 = __builtin_amdgcn_mfma_f32_16x16x32_bf16(a1, bf1, accB1, 0,0,0);\
        accA2 = __builtin_amdgcn_mfma_f32_16x16x32_bf16(a2, bf0, accA2, 0,0,0);\
        accB2 = __builtin_amdgcn_mfma_f32_16x16x32_bf16(a2, bf1, accB2, 0,0,0);\
        accA3 = __builtin_amdgcn_mfma_f32_16x16x32_bf16(a3, bf0, accA3, 0,0,0);\
        accB3 = __builtin_amdgcn_mfma_f32_16x16x32_bf16(a3, bf1, accB3, 0,0,0);\
    }

    #pragma unroll 1
    for (int ks2 = 0; ks2 < 4; ++ks2) {       // 2 k-steps per iteration
        KSTEP(eA0, eA1, 2*ks2)
        if (ks2 < 3) LOADB(eA0, eA1, 2*ks2 + 2)
        KSTEP(eB0, eB1, 2*ks2 + 1)
        if (ks2 < 3) LOADB(eB0, eB1, 2*ks2 + 3)
    }
    #undef KSTEP
    #undef LOADB

    // full x_sq per pixel: reduce over the 4 k-groups
    xsq0 += __shfl_xor(xsq0, 16); xsq0 += __shfl_xor(xsq0, 32);
    xsq1 += __shfl_xor(xsq1, 16); xsq1 += __shfl_xor(xsq1, 32);
    const float xh0 = 0.5f * xsq0;
    const float xh1 = 0.5f * xsq1;

    __syncthreads();   // all waves done reading A -> safe to overlay sSh

    // ---- Phase 3: s_act exchange + evidential scan ----
    const int wpx0 = wu*PXW + col;
    const int wpx1 = wpx0 + 16;
    #define EPI(M, ACC, ACCB)                                                 \
    {                                                                         \
        _Pragma("unroll")                                                     \
        for (int r = 0; r < 4; ++r) {                                         \
            const int p = (M)*16 + kg*4 + r;                                  \
            sSh[p][wpx0] = (_Float16)exp2f(sE2[p] + sG2[p] * (ACC[r]  - xh0));\
            sSh[p][wpx1] = (_Float16)exp2f(sE2[p] + sG2[p] * (ACCB[r] - xh1));\
        }                                                                     \
    }
    EPI(0, accA0, accB0) EPI(1, accA1, accB1)
    EPI(2, accA2, accB2) EPI(3, accA3, accB3)
    #undef EPI
    __syncthreads();

    // sequential evidential scan per pixel (64 steps, registers only)
    if (tid < PXB) {
        float ms0 = 0.f, ms1 = 0.f, mt = 1.f;
        #pragma unroll
        for (int p = 0; p < NP; ++p) {
            const float s   = (float)sSh[p][tid];
            const float mth = 1.f - s;
            const float m0  = s * sU0[p];
            const float m1  = s * sU1[p];
            ms0 = ms0 * (m0 + mth) + m0 * mt;
            ms1 = ms1 * (m1 + mth) + m1 * mt;
            mt *= mth;
        }
        const float inv = 1.f / (ms0 + ms1 + mt + 1e-12f);
        float* __restrict__ op = out + (size_t)b * 3 * HW + hw0 + tid;
        op[0*HW] = ms0 * inv;
        op[1*HW] = ms1 * inv;
        op[2*HW] = mt  * inv;
    }
}

extern "C" void kernel_launch(void* const* d_in, const int* in_sizes, int n_in,
                              void* d_out, int out_size, void* d_ws, size_t ws_size,
                              hipStream_t stream) {
    const float* feats   = (const float*)d_in[0];
    // d_in[1] = geo_context (unused by reference)
    const float* cm      = (const float*)d_in[2];
    const float* alpha   = (const float*)d_in[3];
    const float* gamma_  = (const float*)d_in[4];
    const float* centers = (const float*)d_in[5];
    const float* geo     = (const float*)d_in[6];
    float* out = (float*)d_out;

    const int total = NB * HW;                 // 131072 pixels
    geo_fused<<<total / PXB, 256, 0, stream>>>(feats, cm, alpha, gamma_,
                                               centers, geo, out);
}